// Round 4
// baseline (176.161 us; speedup 1.0000x reference)
//
#include <hip/hip_runtime.h>

// L1Loss: per-(b,c) masked L1 sum / nonzero count, summed over (b,c), / batch.
// B=16, C=64, H=128, W=128 -> 1024 (b,c) pairs x 16384 fp32 elements.
// 201 MB read; ~half L3-resident, half HBM (R1 FETCH_SIZE=100MB). k1 < 40us
// after R2's sched_barrier forced 12 outstanding loads/wave.
// R3: 24 outstanding loads/wave (SPLIT=2, 8 float4/thread/array) -> half the
// vmcnt(0) drain points per byte. VGPR ~110 -> 4 waves/SIMD (occupancy not
// binding per R0->R1). count = sum(mask) since mask is exactly {0,1}.

#define NBC        1024          // B*C
#define SPLIT      2             // blocks per (b,c)
#define NBLK       (NBC * SPLIT) // 2048
#define VEC_PER_BLK 2048         // (128*128/4) / SPLIT float4 per block
#define VEC_PER_THR 8            // VEC_PER_BLK / 256

typedef float v4f __attribute__((ext_vector_type(4)));

__global__ __launch_bounds__(256) void l1_partial_kernel(
    const float* __restrict__ pre,
    const float* __restrict__ gt,
    const float* __restrict__ mask,
    float* __restrict__ s_ws,
    float* __restrict__ c_ws) {
    const int blk = blockIdx.x;                       // 0..2047
    const size_t v4base = (size_t)blk * VEC_PER_BLK;  // float4 index
    const v4f* __restrict__ p4 = (const v4f*)pre  + v4base;
    const v4f* __restrict__ g4 = (const v4f*)gt   + v4base;
    const v4f* __restrict__ m4 = (const v4f*)mask + v4base;

    // Issue all 24 loads before any compute; the fence stops the compiler
    // from re-serializing the batch (R1's VGPR=28 lesson).
    v4f P[VEC_PER_THR], G[VEC_PER_THR], M[VEC_PER_THR];
    #pragma unroll
    for (int k = 0; k < VEC_PER_THR; ++k) {
        const int i = threadIdx.x + k * 256;
        P[k] = __builtin_nontemporal_load(p4 + i);
        G[k] = __builtin_nontemporal_load(g4 + i);
        M[k] = __builtin_nontemporal_load(m4 + i);
    }
    __builtin_amdgcn_sched_barrier(0);   // loads stay batched: 24 in flight

    float s = 0.0f, cnt = 0.0f;
    #pragma unroll
    for (int k = 0; k < VEC_PER_THR; ++k) {
        s += fabsf(P[k].x - G[k].x) * M[k].x
           + fabsf(P[k].y - G[k].y) * M[k].y
           + fabsf(P[k].z - G[k].z) * M[k].z
           + fabsf(P[k].w - G[k].w) * M[k].w;
        // mask is exactly {0,1}: nonzero count == sum of mask values
        cnt += M[k].x + M[k].y + M[k].z + M[k].w;
    }

    // wave-64 butterfly reduce
    #pragma unroll
    for (int off = 32; off > 0; off >>= 1) {
        s   += __shfl_down(s,   off, 64);
        cnt += __shfl_down(cnt, off, 64);
    }

    __shared__ float ss[4];
    __shared__ float sc[4];
    const int wave = threadIdx.x >> 6;
    const int lane = threadIdx.x & 63;
    if (lane == 0) { ss[wave] = s; sc[wave] = cnt; }
    __syncthreads();
    if (threadIdx.x == 0) {
        s_ws[blk] = ss[0] + ss[1] + ss[2] + ss[3];
        c_ws[blk] = sc[0] + sc[1] + sc[2] + sc[3];
    }
}

// One block: fold SPLIT partials per (b,c), divide by clamped count,
// sum 1024 ratios, scale by 1/batch_size.
__global__ __launch_bounds__(256) void l1_final_kernel(
    const float* __restrict__ s_ws,
    const float* __restrict__ c_ws,
    const int* __restrict__ bsz,
    float* __restrict__ out) {
    float acc = 0.0f;
    #pragma unroll
    for (int j = 0; j < NBC / 256; ++j) {
        const int bc = threadIdx.x + j * 256;
        float S = 0.0f, Cn = 0.0f;
        #pragma unroll
        for (int h = 0; h < SPLIT; ++h) {
            S  += s_ws[bc * SPLIT + h];
            Cn += c_ws[bc * SPLIT + h];
        }
        acc += S / fmaxf(Cn, 1.0f);
    }
    #pragma unroll
    for (int off = 32; off > 0; off >>= 1) acc += __shfl_down(acc, off, 64);
    __shared__ float ss[4];
    const int wave = threadIdx.x >> 6;
    const int lane = threadIdx.x & 63;
    if (lane == 0) ss[wave] = acc;
    __syncthreads();
    if (threadIdx.x == 0) {
        out[0] = (ss[0] + ss[1] + ss[2] + ss[3]) / (float)bsz[0];
    }
}

extern "C" void kernel_launch(void* const* d_in, const int* in_sizes, int n_in,
                              void* d_out, int out_size, void* d_ws, size_t ws_size,
                              hipStream_t stream) {
    const float* pre  = (const float*)d_in[0];
    const float* gt   = (const float*)d_in[1];
    const float* mask = (const float*)d_in[2];
    const int*   bsz  = (const int*)d_in[3];
    float* s_ws = (float*)d_ws;          // NBLK floats
    float* c_ws = (float*)d_ws + NBLK;   // NBLK floats (16 KB total)
    float* out  = (float*)d_out;

    l1_partial_kernel<<<NBLK, 256, 0, stream>>>(pre, gt, mask, s_ws, c_ws);
    l1_final_kernel<<<1, 256, 0, stream>>>(s_ws, c_ws, bsz, out);
}